// Round 7
// baseline (623.300 us; speedup 1.0000x reference)
//
#include <hip/hip_runtime.h>
#include <hip/hip_bf16.h>

#define N_NODES 16384
#define FDIM 512

typedef __attribute__((address_space(1))) const void gvoid_t;
typedef __attribute__((address_space(3))) void lvoid_t;

#define SCHED_FENCE() __builtin_amdgcn_sched_barrier(0)

// ---------------- pipelined row-aggregation GEMM: out = [relu](A @ V [+ bias]) ----------------
// A: [N, KTOT] fp32, V: [KTOT, 16] fp32, out: [N, 16].
// 512 threads = 8 waves; 16 rows/block. k-split: waves 0-3 own k-half 0,
// waves 4-7 own k-half 1 of the SAME 16 rows -> each row's 2 KB per tile is
// issued back-to-back by a wave pair (2 KB DRAM bursts vs r6's 1 KB), with
// per-thread registers unchanged vs r6 (acc[4][16]+a_cur[4]+a_next[4] ~115).
// V tiles (KT=512 x 16 = 32 KB) double-buffered (64 KB LDS -> 2 blocks/CU,
// 16 waves/CU), staged via global_load_lds w16 (linear dest + pre-swizzled
// global src). XOR swizzle byte' = byte ^ (((byte>>8)&7)<<4) on [k][c] tile.
// Sync: counted vmcnt(4) + raw s_barrier (A-prefetch for t+1 stays in flight
// across the barrier; never vmcnt(0) in the loop). k-half partials combined
// once at the end via 1 KB LDS exchange.
template <int KTOT, int RELU, int HASBIAS>
__global__ __launch_bounds__(512, 2)
void k_rowagg(const float* __restrict__ A,
              const float* __restrict__ V,
              const float* __restrict__ bias,
              float* __restrict__ out) {
    constexpr int KT = 512;
    constexpr int NT = KTOT / KT;          // 32 for A-passes, 1 for x@W1
    constexpr int TB = KT * 16 * 4;        // 32 KB per buffer
    __shared__ char lv[2 * TB];            // 64 KB

    const int tid = threadIdx.x;
    const int lane = tid & 63;
    const int w3 = (tid >> 6) & 3;         // row-group within block
    const int g = tid >> 8;                // k-half (0 or 1)
    const size_t row0 = (size_t)blockIdx.x * 16 + (size_t)w3 * 4;
    const int khbase = g * 256;

    // pre-swizzled global source dword index per staging slot s:
    // linear LDS dest D = s*8192 + tid*16 ; logical L = D ^ (((D>>8)&7)<<4)
    int sw_src[4];
#pragma unroll
    for (int s = 0; s < 4; ++s) {
        const int D = s * 8192 + tid * 16;
        sw_src[s] = (D ^ (((D >> 8) & 7) << 4)) >> 2;
    }

    unsigned zoff = 0;  // always 0, but opaque to the compiler after each barrier

    auto STAGE = [&](int halfoff, int t) {
        const float* vt = V + (size_t)t * (KT * 16);
#pragma unroll
        for (int s = 0; s < 4; ++s) {
            __builtin_amdgcn_global_load_lds(
                (gvoid_t*)(const void*)(vt + sw_src[s]),
                (lvoid_t*)(void*)(lv + zoff + halfoff + s * 8192 + tid * 16),
                16, 0, 0);
        }
    };

    auto LOADA = [&](float4 (&a)[4], int t) {
        const float* ap = A + (size_t)t * KT + khbase + lane * 4;
#pragma unroll
        for (int r = 0; r < 4; ++r)
            a[r] = *reinterpret_cast<const float4*>(ap + (row0 + r) * (size_t)KTOT);
    };

    float acc[4][16];
#pragma unroll
    for (int r = 0; r < 4; ++r)
#pragma unroll
        for (int c = 0; c < 16; ++c) acc[r][c] = 0.f;

    const unsigned gk = (unsigned)g * 16384u;   // k-half byte offset in tile

    auto COMPUTE = [&](const float4 (&a)[4], unsigned roff) {
#pragma unroll
        for (int kk = 0; kk < 4; ++kk) {
            float4 vv[4];
#pragma unroll
            for (int cc = 0; cc < 4; ++cc) {
                // logical byte B = gk + (4*lane+kk)*64 + cc*16 ; phys = B ^ ((lane&7)<<4)
                const unsigned B = gk + (unsigned)lane * 256u + ((unsigned)kk << 6) +
                                   ((unsigned)cc << 4);
                const unsigned P = B ^ (((unsigned)lane & 7u) << 4);
                vv[cc] = *reinterpret_cast<const float4*>(lv + roff + P);
            }
#pragma unroll
            for (int cc = 0; cc < 4; ++cc) {
#pragma unroll
                for (int r = 0; r < 4; ++r) {
                    const float ak = reinterpret_cast<const float*>(&a[r])[kk];
                    acc[r][cc * 4 + 0] += ak * vv[cc].x;
                    acc[r][cc * 4 + 1] += ak * vv[cc].y;
                    acc[r][cc * 4 + 2] += ak * vv[cc].z;
                    acc[r][cc * 4 + 3] += ak * vv[cc].w;
                }
            }
        }
    };

    float4 a0[4], a1[4];

    // prologue: stage tile 0 -> buf0, prefetch A(0); wait own stage; sync.
    STAGE(0, 0);
    SCHED_FENCE();
    LOADA(a0, 0);
    SCHED_FENCE();
    asm volatile("s_waitcnt vmcnt(4)" ::: "memory");
    __builtin_amdgcn_s_barrier();
    asm volatile("" : "+v"(zoff));
    SCHED_FENCE();

    if (NT > 1) {
#pragma unroll 1
        for (int t = 0; t < NT - 1; t += 2) {
            // even tile t: read buf0, stage tile t+1 -> buf1 (t+1 <= NT-1 by loop bound)
            STAGE(TB, t + 1);
            SCHED_FENCE();
            LOADA(a1, t + 1);
            SCHED_FENCE();
            COMPUTE(a0, zoff + 0);
            SCHED_FENCE();
            asm volatile("s_waitcnt vmcnt(4)" ::: "memory");
            __builtin_amdgcn_s_barrier();
            asm volatile("" : "+v"(zoff));
            SCHED_FENCE();

            // odd tile t+1: read buf1, stage tile t+2 -> buf0 (if any)
            if (t + 2 < NT) {
                STAGE(0, t + 2);
                SCHED_FENCE();
                LOADA(a0, t + 2);
                SCHED_FENCE();
                COMPUTE(a1, zoff + TB);
                SCHED_FENCE();
                asm volatile("s_waitcnt vmcnt(4)" ::: "memory");
                __builtin_amdgcn_s_barrier();
                asm volatile("" : "+v"(zoff));
                SCHED_FENCE();
            } else {
                COMPUTE(a1, zoff + TB);
            }
        }
    } else {
        COMPUTE(a0, zoff + 0);
    }

    // butterfly-reduce the 64 (r,c) partials across the wave; lane v=r*16+c
    // keeps value v. Then combine the two k-half wave groups via LDS.
    float o = 0.f;
#pragma unroll
    for (int r = 0; r < 4; ++r) {
#pragma unroll
        for (int c = 0; c < 16; ++c) {
            float s = acc[r][c];
            s += __shfl_xor(s, 1);  s += __shfl_xor(s, 2);  s += __shfl_xor(s, 4);
            s += __shfl_xor(s, 8);  s += __shfl_xor(s, 16); s += __shfl_xor(s, 32);
            o = (r * 16 + c == lane) ? s : o;
        }
    }
    __syncthreads();                       // all compute done; lv reusable
    float* sc = reinterpret_cast<float*>(lv);
    if (g == 1) sc[w3 * 64 + lane] = o;
    __syncthreads();
    if (g == 0) {
        o += sc[w3 * 64 + lane];
        if (HASBIAS) o += bias[lane & 15];
        if (RELU) o = fmaxf(o, 0.f);
        out[(size_t)blockIdx.x * 256 + w3 * 64 + lane] = o;
    }
}

// ---------------- K3: hw = h1 @ W2  ([N,16]@[16,16]) ----------------
__global__ __launch_bounds__(256) void k3_hw(const float* __restrict__ h1,
                                             const float* __restrict__ W2,
                                             float* __restrict__ hw) {
    __shared__ float w2s[256];
    w2s[threadIdx.x] = W2[threadIdx.x];
    __syncthreads();
    const size_t r = (size_t)blockIdx.x * 256 + threadIdx.x;
    float h[16];
#pragma unroll
    for (int q = 0; q < 4; ++q) {
        float4 v = *reinterpret_cast<const float4*>(h1 + r * 16 + q * 4);
        h[q * 4 + 0] = v.x; h[q * 4 + 1] = v.y; h[q * 4 + 2] = v.z; h[q * 4 + 3] = v.w;
    }
#pragma unroll
    for (int q = 0; q < 4; ++q) {
        float4 o;
#pragma unroll
        for (int j = 0; j < 4; ++j) {
            const int c = q * 4 + j;
            float s = 0.f;
#pragma unroll
            for (int k = 0; k < 16; ++k) s += h[k] * w2s[k * 16 + c];
            (&o.x)[j] = s;
        }
        *reinterpret_cast<float4*>(hw + r * 16 + q * 4) = o;
    }
}

// ---------------- K5: out = softmax(g) @ Wd + bd ----------------
__global__ __launch_bounds__(256) void k5_head(const float* __restrict__ g,
                                               const float* __restrict__ Wd,
                                               const float* __restrict__ bd,
                                               float* __restrict__ out) {
    const size_t r = (size_t)blockIdx.x * 256 + threadIdx.x;
    float v[16];
#pragma unroll
    for (int q = 0; q < 4; ++q) {
        float4 t = *reinterpret_cast<const float4*>(g + r * 16 + q * 4);
        v[q * 4 + 0] = t.x; v[q * 4 + 1] = t.y; v[q * 4 + 2] = t.z; v[q * 4 + 3] = t.w;
    }
    float m = v[0];
#pragma unroll
    for (int c = 1; c < 16; ++c) m = fmaxf(m, v[c]);
    float se = 0.f, sd = 0.f;
#pragma unroll
    for (int c = 0; c < 16; ++c) {
        const float e = expf(v[c] - m);
        se += e;
        sd += e * Wd[c];
    }
    out[r] = sd / se + bd[0];
}

extern "C" void kernel_launch(void* const* d_in, const int* in_sizes, int n_in,
                              void* d_out, int out_size, void* d_ws, size_t ws_size,
                              hipStream_t stream) {
    const float* x  = (const float*)d_in[0];
    const float* A  = (const float*)d_in[1];
    const float* W1 = (const float*)d_in[2];
    const float* b1 = (const float*)d_in[3];
    const float* W2 = (const float*)d_in[4];
    const float* b2 = (const float*)d_in[5];
    const float* Wd = (const float*)d_in[6];
    const float* bd = (const float*)d_in[7];
    float* out = (float*)d_out;

    float* ws = (float*)d_ws;
    float* xw = ws;                        // [N,16] 1 MB
    float* h1 = ws + 1 * N_NODES * 16;     // [N,16] 1 MB
    float* hw = ws + 2 * N_NODES * 16;     // [N,16] 1 MB
    float* gl = ws + 3 * N_NODES * 16;     // [N,16] 1 MB

    // xw = x @ W1   (KTOT=512 -> single tile, NT=1 path)
    k_rowagg<FDIM, 0, 0><<<N_NODES / 16, 512, 0, stream>>>(x, W1, b1, xw);
    // h1 = relu(A @ xw + b1)
    k_rowagg<N_NODES, 1, 1><<<N_NODES / 16, 512, 0, stream>>>(A, xw, b1, h1);
    // hw = h1 @ W2
    k3_hw<<<N_NODES / 256, 256, 0, stream>>>(h1, W2, hw);
    // gl = A @ hw + b2
    k_rowagg<N_NODES, 0, 1><<<N_NODES / 16, 512, 0, stream>>>(A, hw, b2, gl);
    // out = softmax(gl) @ Wd + bd
    k5_head<<<N_NODES / 256, 256, 0, stream>>>(gl, Wd, bd, out);
}

// Round 9
// 460.752 us; speedup vs baseline: 1.3528x; 1.3528x over previous
//
#include <hip/hip_runtime.h>
#include <hip/hip_bf16.h>

#define N_NODES 16384
#define FDIM 512

typedef __attribute__((address_space(1))) const void gvoid_t;
typedef __attribute__((address_space(3))) void lvoid_t;
typedef float vfloat4 __attribute__((ext_vector_type(4)));

#define SCHED_FENCE() __builtin_amdgcn_sched_barrier(0)

// ---------------- pipelined row-aggregation GEMM: out = [relu](A @ V [+ bias]) ----------------
// EXACT r6 structure (500 us total; r7's k-split regressed to 623 and is reverted):
// 4 waves/block, 4 rows/wave, KT=256 double-buffered LDS (2x16 KB -> 4 blocks/CU,
// 16 waves/CU), global_load_lds w16 staging (linear dest + pre-swizzled src),
// XOR-swizzled [k][c] tile, counted vmcnt(4) + raw s_barrier (prefetch stays in
// flight across the barrier).
// SINGLE CHANGE vs r6: A loads via __builtin_nontemporal_load (nt flag) — A is
// 1.07 GB pure-streaming with 0% cache hit; skipping L2/IC line allocation on
// the fill path is the hypothesized route from 4.55 -> ~6 TB/s reads.
// (r8 lesson: the builtin needs clang-native ext_vector_type, not HIP float4.)
template <int KTOT, int RELU, int HASBIAS>
__global__ __launch_bounds__(256, 2)
void k_rowagg(const float* __restrict__ A,
              const float* __restrict__ V,
              const float* __restrict__ bias,
              float* __restrict__ out) {
    constexpr int KT = 256;
    constexpr int NT = KTOT / KT;          // 64 for A-passes, 2 for x@W1 (even!)
    constexpr int TB = KT * 16 * 4;        // 16 KB per buffer
    __shared__ char lv[2 * TB];            // 32 KB

    const int tid = threadIdx.x;
    const int lane = tid & 63;
    const int w = tid >> 6;
    const size_t row0 = (size_t)blockIdx.x * 16 + (size_t)w * 4;

    // pre-swizzled global source dword index per staging slot s:
    // linear LDS dest D = s*4096 + tid*16 ; logical L = D ^ (((D>>8)&7)<<4)
    int sw_src[4];
#pragma unroll
    for (int s = 0; s < 4; ++s) {
        const int D = s * 4096 + tid * 16;
        sw_src[s] = (D ^ (((D >> 8) & 7) << 4)) >> 2;
    }

    unsigned zoff = 0;  // always 0, but opaque to the compiler after each barrier

    auto STAGE = [&](int halfoff, int t) {
        const float* vt = V + (size_t)t * (KT * 16);
#pragma unroll
        for (int s = 0; s < 4; ++s) {
            __builtin_amdgcn_global_load_lds(
                (gvoid_t*)(const void*)(vt + sw_src[s]),
                (lvoid_t*)(void*)(lv + zoff + halfoff + s * 4096 + tid * 16),
                16, 0, 0);
        }
    };

    auto LOADA = [&](vfloat4 (&a)[4], int t) {
#pragma unroll
        for (int r = 0; r < 4; ++r)
            a[r] = __builtin_nontemporal_load(
                reinterpret_cast<const vfloat4*>(
                    A + (row0 + r) * (size_t)KTOT + (size_t)t * KT + lane * 4));
    };

    float acc[4][16];
#pragma unroll
    for (int r = 0; r < 4; ++r)
#pragma unroll
        for (int c = 0; c < 16; ++c) acc[r][c] = 0.f;

    auto COMPUTE = [&](const vfloat4 (&a)[4], unsigned roff) {
#pragma unroll
        for (int kk = 0; kk < 4; ++kk) {
            vfloat4 vv[4];
#pragma unroll
            for (int cc = 0; cc < 4; ++cc) {
                // logical byte B = (4*lane+kk)*64 + cc*16 ; phys = B ^ ((lane&7)<<4)
                const unsigned B = (unsigned)lane * 256u + ((unsigned)kk << 6) +
                                   ((unsigned)cc << 4);
                const unsigned P = B ^ (((unsigned)lane & 7u) << 4);
                vv[cc] = *reinterpret_cast<const vfloat4*>(lv + roff + P);
            }
#pragma unroll
            for (int cc = 0; cc < 4; ++cc) {
#pragma unroll
                for (int r = 0; r < 4; ++r) {
                    const float ak = a[r][kk];
                    acc[r][cc * 4 + 0] += ak * vv[cc][0];
                    acc[r][cc * 4 + 1] += ak * vv[cc][1];
                    acc[r][cc * 4 + 2] += ak * vv[cc][2];
                    acc[r][cc * 4 + 3] += ak * vv[cc][3];
                }
            }
        }
    };

    vfloat4 a0[4], a1[4];

    // prologue: stage tile 0 -> buf0, prefetch A(0); wait own stage; sync.
    STAGE(0, 0);
    SCHED_FENCE();
    LOADA(a0, 0);
    SCHED_FENCE();
    asm volatile("s_waitcnt vmcnt(4)" ::: "memory");
    __builtin_amdgcn_s_barrier();
    asm volatile("" : "+v"(zoff));
    SCHED_FENCE();

#pragma unroll 1
    for (int t = 0; t < NT; t += 2) {
        // even tile t: read buf0, stage tile t+1 -> buf1 (t+1 < NT always: NT even)
        STAGE(TB, t + 1);
        SCHED_FENCE();
        LOADA(a1, t + 1);
        SCHED_FENCE();
        COMPUTE(a0, zoff + 0);
        SCHED_FENCE();
        asm volatile("s_waitcnt vmcnt(4)" ::: "memory");
        __builtin_amdgcn_s_barrier();
        asm volatile("" : "+v"(zoff));
        SCHED_FENCE();

        // odd tile t+1: read buf1, stage tile t+2 -> buf0 (if any)
        if (t + 2 < NT) {
            STAGE(0, t + 2);
            SCHED_FENCE();
            LOADA(a0, t + 2);
            SCHED_FENCE();
            COMPUTE(a1, zoff + TB);
            SCHED_FENCE();
            asm volatile("s_waitcnt vmcnt(4)" ::: "memory");
            __builtin_amdgcn_s_barrier();
            asm volatile("" : "+v"(zoff));
            SCHED_FENCE();
        } else {
            COMPUTE(a1, zoff + TB);
        }
    }

    // butterfly-reduce the 64 (r,c) partials; lane v=r*16+c keeps value v ->
    // one coalesced 256-dword store per block.
    float o = 0.f;
#pragma unroll
    for (int r = 0; r < 4; ++r) {
#pragma unroll
        for (int c = 0; c < 16; ++c) {
            float s = acc[r][c];
            s += __shfl_xor(s, 1);  s += __shfl_xor(s, 2);  s += __shfl_xor(s, 4);
            s += __shfl_xor(s, 8);  s += __shfl_xor(s, 16); s += __shfl_xor(s, 32);
            o = (r * 16 + c == lane) ? s : o;
        }
    }
    if (HASBIAS) o += bias[lane & 15];
    if (RELU) o = fmaxf(o, 0.f);
    out[row0 * 16 + lane] = o;
}

// ---------------- K3: hw = h1 @ W2  ([N,16]@[16,16]) ----------------
__global__ __launch_bounds__(256) void k3_hw(const float* __restrict__ h1,
                                             const float* __restrict__ W2,
                                             float* __restrict__ hw) {
    __shared__ float w2s[256];
    w2s[threadIdx.x] = W2[threadIdx.x];
    __syncthreads();
    const size_t r = (size_t)blockIdx.x * 256 + threadIdx.x;
    float h[16];
#pragma unroll
    for (int q = 0; q < 4; ++q) {
        float4 v = *reinterpret_cast<const float4*>(h1 + r * 16 + q * 4);
        h[q * 4 + 0] = v.x; h[q * 4 + 1] = v.y; h[q * 4 + 2] = v.z; h[q * 4 + 3] = v.w;
    }
#pragma unroll
    for (int q = 0; q < 4; ++q) {
        float4 o;
#pragma unroll
        for (int j = 0; j < 4; ++j) {
            const int c = q * 4 + j;
            float s = 0.f;
#pragma unroll
            for (int k = 0; k < 16; ++k) s += h[k] * w2s[k * 16 + c];
            (&o.x)[j] = s;
        }
        *reinterpret_cast<float4*>(hw + r * 16 + q * 4) = o;
    }
}

// ---------------- K5: out = softmax(g) @ Wd + bd ----------------
__global__ __launch_bounds__(256) void k5_head(const float* __restrict__ g,
                                               const float* __restrict__ Wd,
                                               const float* __restrict__ bd,
                                               float* __restrict__ out) {
    const size_t r = (size_t)blockIdx.x * 256 + threadIdx.x;
    float v[16];
#pragma unroll
    for (int q = 0; q < 4; ++q) {
        float4 t = *reinterpret_cast<const float4*>(g + r * 16 + q * 4);
        v[q * 4 + 0] = t.x; v[q * 4 + 1] = t.y; v[q * 4 + 2] = t.z; v[q * 4 + 3] = t.w;
    }
    float m = v[0];
#pragma unroll
    for (int c = 1; c < 16; ++c) m = fmaxf(m, v[c]);
    float se = 0.f, sd = 0.f;
#pragma unroll
    for (int c = 0; c < 16; ++c) {
        const float e = expf(v[c] - m);
        se += e;
        sd += e * Wd[c];
    }
    out[r] = sd / se + bd[0];
}

extern "C" void kernel_launch(void* const* d_in, const int* in_sizes, int n_in,
                              void* d_out, int out_size, void* d_ws, size_t ws_size,
                              hipStream_t stream) {
    const float* x  = (const float*)d_in[0];
    const float* A  = (const float*)d_in[1];
    const float* W1 = (const float*)d_in[2];
    const float* b1 = (const float*)d_in[3];
    const float* W2 = (const float*)d_in[4];
    const float* b2 = (const float*)d_in[5];
    const float* Wd = (const float*)d_in[6];
    const float* bd = (const float*)d_in[7];
    float* out = (float*)d_out;

    float* ws = (float*)d_ws;
    float* xw = ws;                        // [N,16] 1 MB
    float* h1 = ws + 1 * N_NODES * 16;     // [N,16] 1 MB
    float* hw = ws + 2 * N_NODES * 16;     // [N,16] 1 MB
    float* gl = ws + 3 * N_NODES * 16;     // [N,16] 1 MB

    // xw = x @ W1   (KTOT=512)
    k_rowagg<FDIM, 0, 0><<<N_NODES / 16, 256, 0, stream>>>(x, W1, b1, xw);
    // h1 = relu(A @ xw + b1)
    k_rowagg<N_NODES, 1, 1><<<N_NODES / 16, 256, 0, stream>>>(A, xw, b1, h1);
    // hw = h1 @ W2
    k3_hw<<<N_NODES / 256, 256, 0, stream>>>(h1, W2, hw);
    // gl = A @ hw + b2
    k_rowagg<N_NODES, 0, 1><<<N_NODES / 16, 256, 0, stream>>>(A, hw, b2, gl);
    // out = softmax(gl) @ Wd + bd
    k5_head<<<N_NODES / 256, 256, 0, stream>>>(gl, Wd, bd, out);
}